// Round 1
// baseline (952.506 us; speedup 1.0000x reference)
//
#include <hip/hip_runtime.h>

#define NSTEPS 500
#define DT 1e-3f
#define STIFF 100.0f
#define DAMP 1.0f
#define GZ -9.81f
#define H 128          // number of holes
#define S 512          // H*4 barycentric slots

// ---------------------------------------------------------------------------
// Bulk closed-form integration for nodes with zero cable force:
//   v_T = v0 + T*dt*g ;  p_T = p0 + T*dt*v0 + dt^2*T(T+1)/2 * g
// ---------------------------------------------------------------------------
__global__ void bulk_integrate(const float* __restrict__ pos,
                               const float* __restrict__ vel,
                               float* __restrict__ out, int ncomp) {
    int i = blockIdx.x * blockDim.x + threadIdx.x;
    if (i >= ncomp) return;
    int d = i - (i / 3) * 3;
    float g  = (d == 2) ? GZ : 0.0f;
    float p0 = pos[i];
    float v0 = vel[i];
    const float C1 = (float)NSTEPS * DT;                          // 0.5
    const float C2 = DT * DT * (float)((NSTEPS * (NSTEPS + 1)) / 2); // 0.12525
    out[i]         = p0 + C1 * v0 + C2 * g;   // position
    out[ncomp + i] = v0 + C1 * g;             // velocity
}

// ---------------------------------------------------------------------------
// Exact 500-step simulation of the coupled subsystem (<=512 distinct nodes),
// entirely in LDS. One block, 128 threads (one per hole).
// Deterministic scatter: canonical-slot + duplicate-chain, no atomics.
// ---------------------------------------------------------------------------
__global__ __launch_bounds__(H) void cable_sim(
    const float* __restrict__ node_pos,
    const float* __restrict__ node_vel,
    const int*   __restrict__ hole_idx,
    const float* __restrict__ hole_w,
    const float* __restrict__ inv_mass,
    float* __restrict__ out, int ncomp) {

    __shared__ int   sIdx[S];
    __shared__ int   sCanon[S];   // first slot with same node index
    __shared__ int   sNext[S];    // next slot (>s) with same node index, or -1
    __shared__ float sW[S];
    __shared__ float sIm[S];
    __shared__ float sPos[S][3];  // state lives at canonical slots
    __shared__ float sVel[S][3];
    __shared__ float sC[S][3];    // per-slot force contribution w*hf
    __shared__ float sHp[H][3];
    __shared__ float sHv[H][3];
    __shared__ float sD[H][3];    // STIFF * normalized segment dir, h < H-1

    const int t = threadIdx.x;

    for (int s = t; s < S; s += H) {
        sIdx[s] = hole_idx[s];
        sW[s]   = hole_w[s];
    }
    __syncthreads();

    for (int s = t; s < S; s += H) {
        int id = sIdx[s];
        int c  = s;
        for (int j = 0; j < s; ++j) {
            if (sIdx[j] == id) { c = j; break; }
        }
        sCanon[s] = c;
        int nx = -1;
        for (int j = s + 1; j < S; ++j) {
            if (sIdx[j] == id) { nx = j; break; }
        }
        sNext[s] = nx;
        sIm[s]   = inv_mass[id];
        sPos[s][0] = node_pos[3 * id + 0];
        sPos[s][1] = node_pos[3 * id + 1];
        sPos[s][2] = node_pos[3 * id + 2];
        sVel[s][0] = node_vel[3 * id + 0];
        sVel[s][1] = node_vel[3 * id + 1];
        sVel[s][2] = node_vel[3 * id + 2];
    }
    __syncthreads();

    const int h = t;
    for (int step = 0; step < NSTEPS; ++step) {
        // ---- gather: barycentric hole position / velocity ----
        float px = 0.f, py = 0.f, pz = 0.f, vx = 0.f, vy = 0.f, vz = 0.f;
#pragma unroll
        for (int k = 0; k < 4; ++k) {
            int   s = 4 * h + k;
            int   c = sCanon[s];
            float w = sW[s];
            px += w * sPos[c][0]; py += w * sPos[c][1]; pz += w * sPos[c][2];
            vx += w * sVel[c][0]; vy += w * sVel[c][1]; vz += w * sVel[c][2];
        }
        sHp[h][0] = px; sHp[h][1] = py; sHp[h][2] = pz;
        sHv[h][0] = vx; sHv[h][1] = vy; sHv[h][2] = vz;
        __syncthreads();

        // ---- segment tensions ----
        if (h < H - 1) {
            float sx = sHp[h + 1][0] - px;
            float sy = sHp[h + 1][1] - py;
            float sz = sHp[h + 1][2] - pz;
            float nrm = sqrtf(sx * sx + sy * sy + sz * sz) + 1e-8f;
            float inv = STIFF / nrm;
            sD[h][0] = sx * inv; sD[h][1] = sy * inv; sD[h][2] = sz * inv;
        }
        __syncthreads();

        // ---- per-hole force: tension(s) + damping ----
        float fx = -DAMP * vx, fy = -DAMP * vy, fz = -DAMP * vz;
        if (h < H - 1) { fx += sD[h][0];     fy += sD[h][1];     fz += sD[h][2];     }
        if (h > 0)     { fx -= sD[h - 1][0]; fy -= sD[h - 1][1]; fz -= sD[h - 1][2]; }

        // ---- per-slot contributions (no atomics) ----
#pragma unroll
        for (int k = 0; k < 4; ++k) {
            int   s = 4 * h + k;
            float w = sW[s];
            sC[s][0] = w * fx; sC[s][1] = w * fy; sC[s][2] = w * fz;
        }
        __syncthreads();

        // ---- integrate canonical slots (chain-sum duplicate contributions) ----
        for (int s = t; s < S; s += H) {
            if (sCanon[s] == s) {
                float nfx = sC[s][0], nfy = sC[s][1], nfz = sC[s][2];
                int j = sNext[s];
                while (j >= 0) {
                    nfx += sC[j][0]; nfy += sC[j][1]; nfz += sC[j][2];
                    j = sNext[j];
                }
                float im = sIm[s];
                float v0 = sVel[s][0] + DT * (nfx * im);
                float v1 = sVel[s][1] + DT * (nfy * im);
                float v2 = sVel[s][2] + DT * (nfz * im + GZ);
                sVel[s][0] = v0; sVel[s][1] = v1; sVel[s][2] = v2;
                sPos[s][0] += DT * v0;
                sPos[s][1] += DT * v1;
                sPos[s][2] += DT * v2;
            }
        }
        __syncthreads();
    }

    // ---- write back involved nodes (overwrites bulk results) ----
    for (int s = t; s < S; s += H) {
        if (sCanon[s] == s) {
            int id = sIdx[s];
            out[3 * id + 0] = sPos[s][0];
            out[3 * id + 1] = sPos[s][1];
            out[3 * id + 2] = sPos[s][2];
            out[ncomp + 3 * id + 0] = sVel[s][0];
            out[ncomp + 3 * id + 1] = sVel[s][1];
            out[ncomp + 3 * id + 2] = sVel[s][2];
        }
    }
}

extern "C" void kernel_launch(void* const* d_in, const int* in_sizes, int n_in,
                              void* d_out, int out_size, void* d_ws, size_t ws_size,
                              hipStream_t stream) {
    const float* node_pos = (const float*)d_in[0];
    const float* node_vel = (const float*)d_in[1];
    const int*   hole_idx = (const int*)d_in[2];
    const float* hole_w   = (const float*)d_in[3];
    const float* inv_mass = (const float*)d_in[4];
    float* out = (float*)d_out;

    const int ncomp = in_sizes[0];   // 60000 (= N_NODES*3)

    const int BT = 256;
    bulk_integrate<<<(ncomp + BT - 1) / BT, BT, 0, stream>>>(node_pos, node_vel,
                                                             out, ncomp);
    cable_sim<<<1, H, 0, stream>>>(node_pos, node_vel, hole_idx, hole_w,
                                   inv_mass, out, ncomp);
}

// Round 2
// 704.521 us; speedup vs baseline: 1.3520x; 1.3520x over previous
//
#include <hip/hip_runtime.h>

#define NSTEPS 500
#define DT 1e-3f
#define STIFF 100.0f
#define DAMP 1.0f
#define GZ -9.81f
#define H 128          // holes
#define S 512          // H*4 slots

// ---------------------------------------------------------------------------
// Bulk closed-form integration for nodes with zero cable force:
//   v_T = v0 + T*dt*g ;  p_T = p0 + T*dt*v0 + dt^2*T(T+1)/2 * g
// ---------------------------------------------------------------------------
__global__ void bulk_integrate(const float* __restrict__ pos,
                               const float* __restrict__ vel,
                               float* __restrict__ out, int ncomp) {
    int i = blockIdx.x * blockDim.x + threadIdx.x;
    if (i >= ncomp) return;
    int d = i - (i / 3) * 3;
    float g  = (d == 2) ? GZ : 0.0f;
    float p0 = pos[i];
    float v0 = vel[i];
    const float C1 = (float)NSTEPS * DT;                             // 0.5
    const float C2 = DT * DT * (float)((NSTEPS * (NSTEPS + 1)) / 2); // 0.12525
    out[i]         = p0 + C1 * v0 + C2 * g;   // position
    out[ncomp + i] = v0 + C1 * g;             // velocity
}

// ---------------------------------------------------------------------------
// Coupled subsystem: 500 steps in ONE wave, zero barriers.
// Lane L owns holes 2L, 2L+1 and slots 8L..8L+7; canonical node state lives
// in registers (all slot loops fully unrolled -> static indexing).
// Duplicate node ids handled via LDS mirror + contribution chain (rare path).
// Cross-lane LDS ordering within the lockstep wave: s_waitcnt lgkmcnt(0).
// ---------------------------------------------------------------------------
#define FENCE() asm volatile("s_waitcnt lgkmcnt(0)" ::: "memory")

__global__ __launch_bounds__(256) void cable_sim(
    const float* __restrict__ node_pos,
    const float* __restrict__ node_vel,
    const int*   __restrict__ hole_idx,
    const float* __restrict__ hole_w,
    const float* __restrict__ inv_mass,
    float* __restrict__ out, int ncomp) {

    __shared__ int   sId[S];
    __shared__ int   sCanonL[S];
    __shared__ int   sNextL[S];
    __shared__ float mirror[S][8];   // pos xyz, vel xyz (state of chained canonicals)
    __shared__ float contrib[S][4];  // per-slot w*f (written by dup slots only)

    const int tid = threadIdx.x;

    // ---- load slot node ids ----
    for (int s = tid; s < S; s += 256) sId[s] = hole_idx[s];
    __syncthreads();

    // ---- duplicate scan: canon = first slot with same id; next = next one ----
    {
        int s0 = 2 * tid, s1 = s0 + 1;
        int id0 = sId[s0], id1 = sId[s1];
        int c0 = S, c1 = S, n0 = S, n1 = S;
        for (int j = 0; j < S; ++j) {
            int idj = sId[j];
            if (idj == id0) { if (j < c0) c0 = j; if (j > s0 && j < n0) n0 = j; }
            if (idj == id1) { if (j < c1) c1 = j; if (j > s1 && j < n1) n1 = j; }
        }
        sCanonL[s0] = c0;            sCanonL[s1] = c1;
        sNextL[s0] = (n0 == S) ? -1 : n0;
        sNextL[s1] = (n1 == S) ? -1 : n1;
    }
    __syncthreads();

    if (tid >= 64) return;           // no barriers below: safe for waves 1-3 to exit
    const int L = tid;

    // ---- per-lane register state for 8 slots ----
    int   nid[8], cslot[8];
    float w8[8], im8[8];
    float px[8], py[8], pz[8], vx8[8], vy8[8], vz8[8];
    int selfM = 0, chainM = 0;

#pragma unroll
    for (int k = 0; k < 8; ++k) {
        int s = 8 * L + k;
        int c = sCanonL[s];
        cslot[k] = c;
        int id = sId[s];
        nid[k] = id;
        w8[k]  = hole_w[s];
        im8[k] = inv_mass[id];
        bool sc = (c == s);
        bool hc = sc && (sNextL[s] >= 0);
        selfM  |= (int)sc << k;
        chainM |= (int)hc << k;
        px[k]  = node_pos[3 * id + 0];
        py[k]  = node_pos[3 * id + 1];
        pz[k]  = node_pos[3 * id + 2];
        vx8[k] = node_vel[3 * id + 0];
        vy8[k] = node_vel[3 * id + 1];
        vz8[k] = node_vel[3 * id + 2];
        if (hc) {
            float* m = &mirror[s][0];
            m[0] = px[k];  m[1] = py[k];  m[2] = pz[k];
            m[3] = vx8[k]; m[4] = vy8[k]; m[5] = vz8[k];
        }
    }
    FENCE();

    const bool firstLane = (L == 0);
    const bool lastLane  = (L == 63);

    for (int step = 0; step < NSTEPS; ++step) {
        // ---- gather: hole pos/vel (registers; LDS mirror for rare dups) ----
        float p0x = 0.f, p0y = 0.f, p0z = 0.f, u0x = 0.f, u0y = 0.f, u0z = 0.f;
        float p1x = 0.f, p1y = 0.f, p1z = 0.f, u1x = 0.f, u1y = 0.f, u1z = 0.f;
#pragma unroll
        for (int k = 0; k < 8; ++k) {
            float gx, gy, gz, hx, hy, hz;
            if ((selfM >> k) & 1) {
                gx = px[k];  gy = py[k];  gz = pz[k];
                hx = vx8[k]; hy = vy8[k]; hz = vz8[k];
            } else {
                const float* m = &mirror[cslot[k]][0];
                gx = m[0]; gy = m[1]; gz = m[2];
                hx = m[3]; hy = m[4]; hz = m[5];
            }
            float ww = w8[k];
            if (k < 4) {
                p0x += ww * gx; p0y += ww * gy; p0z += ww * gz;
                u0x += ww * hx; u0y += ww * hy; u0z += ww * hz;
            } else {
                p1x += ww * gx; p1y += ww * gy; p1z += ww * gz;
                u1x += ww * hx; u1y += ww * hy; u1z += ww * hz;
            }
        }

        // ---- neighbor hole position (hole 2L+2 = lane L+1's hole0) ----
        float qx = __shfl_down(p0x, 1);
        float qy = __shfl_down(p0y, 1);
        float qz = __shfl_down(p0z, 1);

        // ---- segment tensions ----
        float s0x = p1x - p0x, s0y = p1y - p0y, s0z = p1z - p0z;
        float n0 = __builtin_amdgcn_sqrtf(s0x * s0x + s0y * s0y + s0z * s0z);
        float i0 = STIFF * __builtin_amdgcn_rcpf(n0 + 1e-8f);
        float D0x = s0x * i0, D0y = s0y * i0, D0z = s0z * i0;   // segment 2L

        float s1x = qx - p1x, s1y = qy - p1y, s1z = qz - p1z;
        float n1 = __builtin_amdgcn_sqrtf(s1x * s1x + s1y * s1y + s1z * s1z);
        float i1 = STIFF * __builtin_amdgcn_rcpf(n1 + 1e-8f);
        float D1x = s1x * i1, D1y = s1y * i1, D1z = s1z * i1;   // segment 2L+1

        // ---- previous-segment tension for hole 2L (lane L-1's D1) ----
        float ex = __shfl_up(D1x, 1);
        float ey = __shfl_up(D1y, 1);
        float ez = __shfl_up(D1z, 1);

        float f0x = D0x - (firstLane ? 0.f : ex) - DAMP * u0x;
        float f0y = D0y - (firstLane ? 0.f : ey) - DAMP * u0y;
        float f0z = D0z - (firstLane ? 0.f : ez) - DAMP * u0z;
        float f1x = (lastLane ? 0.f : D1x) - D0x - DAMP * u1x;
        float f1y = (lastLane ? 0.f : D1y) - D0y - DAMP * u1y;
        float f1z = (lastLane ? 0.f : D1z) - D0z - DAMP * u1z;

        // ---- per-slot contributions; dups publish to LDS ----
        float cx[8], cy[8], cz[8];
#pragma unroll
        for (int k = 0; k < 8; ++k) {
            float fx = (k < 4) ? f0x : f1x;
            float fy = (k < 4) ? f0y : f1y;
            float fz = (k < 4) ? f0z : f1z;
            cx[k] = w8[k] * fx; cy[k] = w8[k] * fy; cz[k] = w8[k] * fz;
            if (!((selfM >> k) & 1)) {
                float* cp = &contrib[8 * L + k][0];
                cp[0] = cx[k]; cp[1] = cy[k]; cp[2] = cz[k];
            }
        }
        FENCE();

        // ---- chain-sum duplicates, integrate (semi-implicit Euler) ----
#pragma unroll
        for (int k = 0; k < 8; ++k) {
            float nfx = cx[k], nfy = cy[k], nfz = cz[k];
            if ((chainM >> k) & 1) {
                int j = sNextL[8 * L + k];
                do {
                    nfx += contrib[j][0];
                    nfy += contrib[j][1];
                    nfz += contrib[j][2];
                    j = sNextL[j];
                } while (j >= 0);
            }
            float iv = im8[k];
            vx8[k] += DT * (nfx * iv);
            vy8[k] += DT * (nfy * iv);
            vz8[k] += DT * (nfz * iv + GZ);
            px[k] += DT * vx8[k];
            py[k] += DT * vy8[k];
            pz[k] += DT * vz8[k];
            if ((chainM >> k) & 1) {
                float* m = &mirror[8 * L + k][0];
                m[0] = px[k];  m[1] = py[k];  m[2] = pz[k];
                m[3] = vx8[k]; m[4] = vy8[k]; m[5] = vz8[k];
            }
        }
        FENCE();
    }

    // ---- write back canonical nodes (overwrites bulk results) ----
#pragma unroll
    for (int k = 0; k < 8; ++k) {
        if ((selfM >> k) & 1) {
            int id = nid[k];
            out[3 * id + 0] = px[k];
            out[3 * id + 1] = py[k];
            out[3 * id + 2] = pz[k];
            out[ncomp + 3 * id + 0] = vx8[k];
            out[ncomp + 3 * id + 1] = vy8[k];
            out[ncomp + 3 * id + 2] = vz8[k];
        }
    }
}

extern "C" void kernel_launch(void* const* d_in, const int* in_sizes, int n_in,
                              void* d_out, int out_size, void* d_ws, size_t ws_size,
                              hipStream_t stream) {
    const float* node_pos = (const float*)d_in[0];
    const float* node_vel = (const float*)d_in[1];
    const int*   hole_idx = (const int*)d_in[2];
    const float* hole_w   = (const float*)d_in[3];
    const float* inv_mass = (const float*)d_in[4];
    float* out = (float*)d_out;

    const int ncomp = in_sizes[0];   // 60000 (= N_NODES*3)

    const int BT = 256;
    bulk_integrate<<<(ncomp + BT - 1) / BT, BT, 0, stream>>>(node_pos, node_vel,
                                                             out, ncomp);
    cable_sim<<<1, 256, 0, stream>>>(node_pos, node_vel, hole_idx, hole_w,
                                     inv_mass, out, ncomp);
}

// Round 3
// 255.414 us; speedup vs baseline: 3.7293x; 2.7584x over previous
//
#include <hip/hip_runtime.h>

#define NSTEPS 500
#define DT 1e-3f
#define STIFF 100.0f
#define GZ -9.81f
#define H 128          // holes
#define S 512          // H*4 slots
#define MAXC 12        // max tracked couplings per hole (expected <=2)

// ---------------------------------------------------------------------------
// Bulk closed-form integration for nodes with zero cable force:
//   v_T = v0 + T*dt*g ;  p_T = p0 + T*dt*v0 + dt^2*T(T+1)/2 * g
// ---------------------------------------------------------------------------
__global__ void bulk_integrate(const float* __restrict__ pos,
                               const float* __restrict__ vel,
                               float* __restrict__ out, int ncomp) {
    int i = blockIdx.x * blockDim.x + threadIdx.x;
    if (i >= ncomp) return;
    int d = i - (i / 3) * 3;
    float g  = (d == 2) ? GZ : 0.0f;
    float p0 = pos[i];
    float v0 = vel[i];
    const float C1 = (float)NSTEPS * DT;                             // 0.5
    const float C2 = DT * DT * (float)((NSTEPS * (NSTEPS + 1)) / 2); // 0.12525
    out[i]         = p0 + C1 * v0 + C2 * g;   // position
    out[ncomp + i] = v0 + C1 * g;             // velocity
}

// ---------------------------------------------------------------------------
// Hole-space dynamics:  hp = B p, hv = B v,  M = B diag(im) B^T.
//   f_t from (hp,hv);  hv += dt*(M f + sw*g);  hp += dt*hv
//   A1 = sum f_t ; A2 = sum of running sums of f
// Node recovery:
//   v_T = v0 + T dt g + dt im (B^T A1)
//   p_T = p0 + T dt v0 + dt^2 T(T+1)/2 g + dt^2 im (B^T A2)
// One wave runs the 500-step loop; M is diagonal + rare sparse couplings.
// ---------------------------------------------------------------------------
#define FENCE() asm volatile("s_waitcnt lgkmcnt(0)" ::: "memory")

__global__ __launch_bounds__(256) void cable_sim(
    const float* __restrict__ node_pos,
    const float* __restrict__ node_vel,
    const int*   __restrict__ hole_idx,
    const float* __restrict__ hole_w,
    const float* __restrict__ inv_mass,
    float* __restrict__ out, int ncomp) {

    __shared__ int   sId[S];
    __shared__ float sW[S];
    __shared__ float sIm[S];
    __shared__ int   sCanon[S];
    __shared__ int   sNext[S];
    __shared__ float hpH[H][4], hvH[H][4];
    __shared__ float dDiag[H];
    __shared__ float swH[H];
    __shared__ int   cCnt[H];
    __shared__ int   cPart[H][MAXC];
    __shared__ float cCoef[H][MAXC];
    __shared__ float fH[3][H];       // published per-hole forces (hot loop)
    __shared__ float A1H[H][4], A2H[H][4];

    const int tid = threadIdx.x;

    for (int s = tid; s < S; s += 256) {
        int id = hole_idx[s];
        sId[s] = id;
        sW[s]  = hole_w[s];
        sIm[s] = inv_mass[id];
    }
    __syncthreads();

    // ---- per-slot canonical/next chains (for final node writeback) ----
    {
        int s0 = 2 * tid, s1 = s0 + 1;
        int id0 = sId[s0], id1 = sId[s1];
        int c0 = S, c1 = S, n0 = S, n1 = S;
        for (int j = 0; j < S; ++j) {
            int idj = sId[j];
            if (idj == id0) { if (j < c0) c0 = j; if (j > s0 && j < n0) n0 = j; }
            if (idj == id1) { if (j < c1) c1 = j; if (j > s1 && j < n1) n1 = j; }
        }
        sCanon[s0] = c0;             sCanon[s1] = c1;
        sNext[s0] = (n0 == S) ? -1 : n0;
        sNext[s1] = (n1 == S) ? -1 : n1;
    }

    // ---- per-hole precompute: diag(M), couplings, sum(w), hp0, hv0 ----
    if (tid < H) {
        const int h = tid;
        int myId[4]; float myW[4];
#pragma unroll
        for (int k = 0; k < 4; ++k) { myId[k] = sId[4 * h + k]; myW[k] = sW[4 * h + k]; }
        float dg = 0.f, sw = 0.f;
#pragma unroll
        for (int k = 0; k < 4; ++k) {
            sw += myW[k];
            float imk = sIm[4 * h + k];
#pragma unroll
            for (int l = 0; l < 4; ++l)
                if (myId[k] == myId[l]) dg += myW[k] * myW[l] * imk;
        }
        dDiag[h] = dg;
        swH[h]   = sw;

        int cnt = 0;
        for (int j = 0; j < S; ++j) {
            int hj = j >> 2;
            if (hj == h) continue;
            int idj = sId[j];
            float c = 0.f;
#pragma unroll
            for (int k = 0; k < 4; ++k)
                if (myId[k] == idj) c += myW[k];
            if (c != 0.f) {
                c *= sW[j] * sIm[j];
                int found = -1;
                for (int i = 0; i < cnt; ++i)
                    if (cPart[h][i] == hj) { found = i; break; }
                if (found >= 0) cCoef[h][found] += c;
                else if (cnt < MAXC) { cPart[h][cnt] = hj; cCoef[h][cnt] = c; ++cnt; }
            }
        }
        cCnt[h] = cnt;

        float hx = 0, hy = 0, hz = 0, ux = 0, uy = 0, uz = 0;
#pragma unroll
        for (int k = 0; k < 4; ++k) {
            int id = myId[k]; float w = myW[k];
            hx += w * node_pos[3 * id + 0]; hy += w * node_pos[3 * id + 1]; hz += w * node_pos[3 * id + 2];
            ux += w * node_vel[3 * id + 0]; uy += w * node_vel[3 * id + 1]; uz += w * node_vel[3 * id + 2];
        }
        hpH[h][0] = hx; hpH[h][1] = hy; hpH[h][2] = hz;
        hvH[h][0] = ux; hvH[h][1] = uy; hvH[h][2] = uz;
    }
    __syncthreads();

    if (tid >= 64) return;           // single wave from here; no barriers below
    const int L  = tid;
    const int h0 = 2 * L, h1 = 2 * L + 1;

    float hp0x = hpH[h0][0], hp0y = hpH[h0][1], hp0z = hpH[h0][2];
    float hp1x = hpH[h1][0], hp1y = hpH[h1][1], hp1z = hpH[h1][2];
    float u0x  = hvH[h0][0], u0y  = hvH[h0][1], u0z  = hvH[h0][2];
    float u1x  = hvH[h1][0], u1y  = hvH[h1][1], u1z  = hvH[h1][2];
    const float d0  = dDiag[h0], d1 = dDiag[h1];
    const float gz0 = swH[h0] * GZ, gz1 = swH[h1] * GZ;
    const float m0  = (L == 0)  ? 0.f : 1.f;   // no upstream segment at hole 0
    const float m1  = (L == 63) ? 0.f : 1.f;   // no downstream segment at hole 127

    const int cnt0 = cCnt[h0], cnt1 = cCnt[h1];
    int   pA0 = 0, pA1 = 0, pB0 = 0, pB1 = 0;
    float cA0 = 0.f, cA1 = 0.f, cB0 = 0.f, cB1 = 0.f;
    if (cnt0 > 0) { pA0 = cPart[h0][0]; cA0 = cCoef[h0][0]; }
    if (cnt0 > 1) { pA1 = cPart[h0][1]; cA1 = cCoef[h0][1]; }
    if (cnt1 > 0) { pB0 = cPart[h1][0]; cB0 = cCoef[h1][0]; }
    if (cnt1 > 1) { pB1 = cPart[h1][1]; cB1 = cCoef[h1][1]; }

    float A10x = 0.f, A10y = 0.f, A10z = 0.f, A11x = 0.f, A11y = 0.f, A11z = 0.f;
    float A20x = 0.f, A20y = 0.f, A20z = 0.f, A21x = 0.f, A21y = 0.f, A21z = 0.f;

    // software-pipelined neighbor hp (hole 2L+2 = lane L+1's hole0)
    float qx = __shfl_down(hp0x, 1);
    float qy = __shfl_down(hp0y, 1);
    float qz = __shfl_down(hp0z, 1);

    for (int step = 0; step < NSTEPS; ++step) {
        // ---- segment tensions ----
        float s0x = hp1x - hp0x, s0y = hp1y - hp0y, s0z = hp1z - hp0z;
        float n0 = __builtin_amdgcn_sqrtf(s0x * s0x + s0y * s0y + s0z * s0z);
        float i0 = STIFF * __builtin_amdgcn_rcpf(n0 + 1e-8f);
        float D0x = s0x * i0, D0y = s0y * i0, D0z = s0z * i0;     // segment 2L

        float s1x = qx - hp1x, s1y = qy - hp1y, s1z = qz - hp1z;
        float n1 = __builtin_amdgcn_sqrtf(s1x * s1x + s1y * s1y + s1z * s1z);
        float i1 = STIFF * __builtin_amdgcn_rcpf(n1 + 1e-8f);
        float D1x = s1x * i1, D1y = s1y * i1, D1z = s1z * i1;     // segment 2L+1

        float ex = __shfl_up(D1x, 1);
        float ey = __shfl_up(D1y, 1);
        float ez = __shfl_up(D1z, 1);

        // ---- per-hole forces (DAMP == 1) ----
        float f0x = D0x - m0 * ex - u0x;
        float f0y = D0y - m0 * ey - u0y;
        float f0z = D0z - m0 * ez - u0z;
        float f1x = m1 * D1x - D0x - u1x;
        float f1y = m1 * D1y - D0y - u1y;
        float f1z = m1 * D1z - D0z - u1z;

        // ---- publish f for sparse couplings ----
        *(float2*)&fH[0][h0] = make_float2(f0x, f1x);
        *(float2*)&fH[1][h0] = make_float2(f0y, f1y);
        *(float2*)&fH[2][h0] = make_float2(f0z, f1z);
        FENCE();

        // ---- M f = diag + rare off-diagonal ----
        float Mf0x = d0 * f0x, Mf0y = d0 * f0y, Mf0z = d0 * f0z;
        float Mf1x = d1 * f1x, Mf1y = d1 * f1y, Mf1z = d1 * f1z;
        if (cnt0 > 0) {
            Mf0x += cA0 * fH[0][pA0]; Mf0y += cA0 * fH[1][pA0]; Mf0z += cA0 * fH[2][pA0];
            if (cnt0 > 1) {
                Mf0x += cA1 * fH[0][pA1]; Mf0y += cA1 * fH[1][pA1]; Mf0z += cA1 * fH[2][pA1];
                for (int i = 2; i < cnt0; ++i) {
                    int ph = cPart[h0][i]; float cf = cCoef[h0][i];
                    Mf0x += cf * fH[0][ph]; Mf0y += cf * fH[1][ph]; Mf0z += cf * fH[2][ph];
                }
            }
        }
        if (cnt1 > 0) {
            Mf1x += cB0 * fH[0][pB0]; Mf1y += cB0 * fH[1][pB0]; Mf1z += cB0 * fH[2][pB0];
            if (cnt1 > 1) {
                Mf1x += cB1 * fH[0][pB1]; Mf1y += cB1 * fH[1][pB1]; Mf1z += cB1 * fH[2][pB1];
                for (int i = 2; i < cnt1; ++i) {
                    int ph = cPart[h1][i]; float cf = cCoef[h1][i];
                    Mf1x += cf * fH[0][ph]; Mf1y += cf * fH[1][ph]; Mf1z += cf * fH[2][ph];
                }
            }
        }

        // ---- integrate hole state ----
        u0x += DT * Mf0x; u0y += DT * Mf0y; u0z += DT * (Mf0z + gz0);
        u1x += DT * Mf1x; u1y += DT * Mf1y; u1z += DT * (Mf1z + gz1);
        hp0x += DT * u0x; hp0y += DT * u0y; hp0z += DT * u0z;
        hp1x += DT * u1x; hp1y += DT * u1y; hp1z += DT * u1z;

        // ---- next iteration's neighbor hp (overlaps with accumulators) ----
        qx = __shfl_down(hp0x, 1);
        qy = __shfl_down(hp0y, 1);
        qz = __shfl_down(hp0z, 1);

        // ---- force accumulators ----
        A10x += f0x; A10y += f0y; A10z += f0z;
        A11x += f1x; A11y += f1y; A11z += f1z;
        A20x += A10x; A20y += A10y; A20z += A10z;
        A21x += A11x; A21y += A11y; A21z += A11z;
    }

    // ---- publish accumulators, recover node states ----
    *(float4*)&A1H[h0][0] = make_float4(A10x, A10y, A10z, 0.f);
    *(float4*)&A1H[h1][0] = make_float4(A11x, A11y, A11z, 0.f);
    *(float4*)&A2H[h0][0] = make_float4(A20x, A20y, A20z, 0.f);
    *(float4*)&A2H[h1][0] = make_float4(A21x, A21y, A21z, 0.f);
    FENCE();

    const float C1 = (float)NSTEPS * DT;                             // 0.5
    const float C2 = DT * DT * (float)((NSTEPS * (NSTEPS + 1)) / 2); // 0.12525
#pragma unroll
    for (int k = 0; k < 8; ++k) {
        int s = 8 * L + k;
        if (sCanon[s] == s) {
            int id = sId[s];
            float aVx = 0.f, aVy = 0.f, aVz = 0.f, aPx = 0.f, aPy = 0.f, aPz = 0.f;
            int j = s;
            do {
                int hj = j >> 2;
                float w = sW[j];
                aVx += w * A1H[hj][0]; aVy += w * A1H[hj][1]; aVz += w * A1H[hj][2];
                aPx += w * A2H[hj][0]; aPy += w * A2H[hj][1]; aPz += w * A2H[hj][2];
                j = sNext[j];
            } while (j >= 0);
            float im = sIm[s];
            float p0x = node_pos[3 * id + 0], p0y = node_pos[3 * id + 1], p0z = node_pos[3 * id + 2];
            float v0x = node_vel[3 * id + 0], v0y = node_vel[3 * id + 1], v0z = node_vel[3 * id + 2];
            out[3 * id + 0] = p0x + C1 * v0x + (DT * DT) * im * aPx;
            out[3 * id + 1] = p0y + C1 * v0y + (DT * DT) * im * aPy;
            out[3 * id + 2] = p0z + C1 * v0z + C2 * GZ + (DT * DT) * im * aPz;
            out[ncomp + 3 * id + 0] = v0x + DT * im * aVx;
            out[ncomp + 3 * id + 1] = v0y + DT * im * aVy;
            out[ncomp + 3 * id + 2] = v0z + C1 * GZ + DT * im * aVz;
        }
    }
}

extern "C" void kernel_launch(void* const* d_in, const int* in_sizes, int n_in,
                              void* d_out, int out_size, void* d_ws, size_t ws_size,
                              hipStream_t stream) {
    const float* node_pos = (const float*)d_in[0];
    const float* node_vel = (const float*)d_in[1];
    const int*   hole_idx = (const int*)d_in[2];
    const float* hole_w   = (const float*)d_in[3];
    const float* inv_mass = (const float*)d_in[4];
    float* out = (float*)d_out;

    const int ncomp = in_sizes[0];   // 60000 (= N_NODES*3)

    const int BT = 256;
    bulk_integrate<<<(ncomp + BT - 1) / BT, BT, 0, stream>>>(node_pos, node_vel,
                                                             out, ncomp);
    cable_sim<<<1, 256, 0, stream>>>(node_pos, node_vel, hole_idx, hole_w,
                                     inv_mass, out, ncomp);
}

// Round 4
// 239.351 us; speedup vs baseline: 3.9795x; 1.0671x over previous
//
#include <hip/hip_runtime.h>

#define NSTEPS 500
#define DT 1e-3f
#define STIFF 100.0f
#define GZ -9.81f
#define H 128          // holes
#define S 512          // H*4 slots
#define MAXC 12        // max tracked couplings per hole (expected <=2)

// ---------------------------------------------------------------------------
// Bulk closed-form integration for nodes with zero cable force:
//   v_T = v0 + T*dt*g ;  p_T = p0 + T*dt*v0 + dt^2*T(T+1)/2 * g
// ---------------------------------------------------------------------------
__global__ void bulk_integrate(const float* __restrict__ pos,
                               const float* __restrict__ vel,
                               float* __restrict__ out, int ncomp) {
    int i = blockIdx.x * blockDim.x + threadIdx.x;
    if (i >= ncomp) return;
    int d = i - (i / 3) * 3;
    float g  = (d == 2) ? GZ : 0.0f;
    float p0 = pos[i];
    float v0 = vel[i];
    const float C1 = (float)NSTEPS * DT;                             // 0.5
    const float C2 = DT * DT * (float)((NSTEPS * (NSTEPS + 1)) / 2); // 0.12525
    out[i]         = p0 + C1 * v0 + C2 * g;   // position
    out[ncomp + i] = v0 + C1 * g;             // velocity
}

// ---------------------------------------------------------------------------
// Hole-space dynamics in ONE wave; +-1 lane exchange via DPP (VALU pipe),
// not ds_permute.  wave_shr:1 (0x138) = value from lane-1 ; wave_shl:1
// (0x130) = value from lane+1 ; bound_ctrl:0 -> out-of-range lanes read 0.
// ---------------------------------------------------------------------------
__device__ __forceinline__ float dpp_up1(float x) {   // lane i <- lane i-1
    return __int_as_float(__builtin_amdgcn_update_dpp(
        0, __float_as_int(x), 0x138, 0xF, 0xF, true));
}
__device__ __forceinline__ float dpp_down1(float x) { // lane i <- lane i+1
    return __int_as_float(__builtin_amdgcn_update_dpp(
        0, __float_as_int(x), 0x130, 0xF, 0xF, true));
}

#define FENCE() asm volatile("s_waitcnt lgkmcnt(0)" ::: "memory")

__global__ __launch_bounds__(256) void cable_sim(
    const float* __restrict__ node_pos,
    const float* __restrict__ node_vel,
    const int*   __restrict__ hole_idx,
    const float* __restrict__ hole_w,
    const float* __restrict__ inv_mass,
    float* __restrict__ out, int ncomp) {

    __shared__ int   sId[S];
    __shared__ float sW[S];
    __shared__ float sIm[S];
    __shared__ int   sCanon[S];
    __shared__ int   sNext[S];
    __shared__ float hpH[H][4], hvH[H][4];
    __shared__ float dDiag[H];
    __shared__ float swH[H];
    __shared__ int   cCnt[H];
    __shared__ int   cPart[H][MAXC];
    __shared__ float cCoef[H][MAXC];
    __shared__ float fH[3][H];       // published per-hole forces (rare path)
    __shared__ float A1H[H][4], A2H[H][4];

    const int tid = threadIdx.x;

    for (int s = tid; s < S; s += 256) {
        int id = hole_idx[s];
        sId[s] = id;
        sW[s]  = hole_w[s];
        sIm[s] = inv_mass[id];
    }
    __syncthreads();

    // ---- per-slot canonical/next chains (for final node writeback) ----
    {
        int s0 = 2 * tid, s1 = s0 + 1;
        int id0 = sId[s0], id1 = sId[s1];
        int c0 = S, c1 = S, n0 = S, n1 = S;
        for (int j = 0; j < S; ++j) {
            int idj = sId[j];
            if (idj == id0) { if (j < c0) c0 = j; if (j > s0 && j < n0) n0 = j; }
            if (idj == id1) { if (j < c1) c1 = j; if (j > s1 && j < n1) n1 = j; }
        }
        sCanon[s0] = c0;             sCanon[s1] = c1;
        sNext[s0] = (n0 == S) ? -1 : n0;
        sNext[s1] = (n1 == S) ? -1 : n1;
    }

    // ---- per-hole precompute: diag(M), couplings, sum(w), hp0, hv0 ----
    if (tid < H) {
        const int h = tid;
        int myId[4]; float myW[4];
#pragma unroll
        for (int k = 0; k < 4; ++k) { myId[k] = sId[4 * h + k]; myW[k] = sW[4 * h + k]; }
        float dg = 0.f, sw = 0.f;
#pragma unroll
        for (int k = 0; k < 4; ++k) {
            sw += myW[k];
            float imk = sIm[4 * h + k];
#pragma unroll
            for (int l = 0; l < 4; ++l)
                if (myId[k] == myId[l]) dg += myW[k] * myW[l] * imk;
        }
        dDiag[h] = dg;
        swH[h]   = sw;

        int cnt = 0;
        for (int j = 0; j < S; ++j) {
            int hj = j >> 2;
            if (hj == h) continue;
            int idj = sId[j];
            float c = 0.f;
#pragma unroll
            for (int k = 0; k < 4; ++k)
                if (myId[k] == idj) c += myW[k];
            if (c != 0.f) {
                c *= sW[j] * sIm[j];
                int found = -1;
                for (int i = 0; i < cnt; ++i)
                    if (cPart[h][i] == hj) { found = i; break; }
                if (found >= 0) cCoef[h][found] += c;
                else if (cnt < MAXC) { cPart[h][cnt] = hj; cCoef[h][cnt] = c; ++cnt; }
            }
        }
        cCnt[h] = cnt;

        float hx = 0, hy = 0, hz = 0, ux = 0, uy = 0, uz = 0;
#pragma unroll
        for (int k = 0; k < 4; ++k) {
            int id = myId[k]; float w = myW[k];
            hx += w * node_pos[3 * id + 0]; hy += w * node_pos[3 * id + 1]; hz += w * node_pos[3 * id + 2];
            ux += w * node_vel[3 * id + 0]; uy += w * node_vel[3 * id + 1]; uz += w * node_vel[3 * id + 2];
        }
        hpH[h][0] = hx; hpH[h][1] = hy; hpH[h][2] = hz;
        hvH[h][0] = ux; hvH[h][1] = uy; hvH[h][2] = uz;
    }
    __syncthreads();

    if (tid >= 64) return;           // single wave from here; no barriers below
    const int L  = tid;
    const int h0 = 2 * L, h1 = 2 * L + 1;

    float hp0x = hpH[h0][0], hp0y = hpH[h0][1], hp0z = hpH[h0][2];
    float hp1x = hpH[h1][0], hp1y = hpH[h1][1], hp1z = hpH[h1][2];
    float u0x  = hvH[h0][0], u0y  = hvH[h0][1], u0z  = hvH[h0][2];
    float u1x  = hvH[h1][0], u1y  = hvH[h1][1], u1z  = hvH[h1][2];
    const float d0  = dDiag[h0], d1 = dDiag[h1];
    const float gz0 = swH[h0] * GZ, gz1 = swH[h1] * GZ;  // add to Mf_z pre-dt
    const float m1  = (L == 63) ? 0.f : 1.f;   // no downstream segment at 127

    const int cnt0 = cCnt[h0], cnt1 = cCnt[h1];
    int   pA0 = 0, pA1 = 0, pB0 = 0, pB1 = 0;
    float cA0 = 0.f, cA1 = 0.f, cB0 = 0.f, cB1 = 0.f;
    if (cnt0 > 0) { pA0 = cPart[h0][0]; cA0 = cCoef[h0][0]; }
    if (cnt0 > 1) { pA1 = cPart[h0][1]; cA1 = cCoef[h0][1]; }
    if (cnt1 > 0) { pB0 = cPart[h1][0]; cB0 = cCoef[h1][0]; }
    if (cnt1 > 1) { pB1 = cPart[h1][1]; cB1 = cCoef[h1][1]; }
    const bool anyC = __any(cnt0 > 0 || cnt1 > 0);   // wave-uniform

    float A10x = 0.f, A10y = 0.f, A10z = 0.f, A11x = 0.f, A11y = 0.f, A11z = 0.f;
    float A20x = 0.f, A20y = 0.f, A20z = 0.f, A21x = 0.f, A21y = 0.f, A21z = 0.f;

#pragma unroll 2
    for (int step = 0; step < NSTEPS; ++step) {
        // ---- neighbor hole position (hole 2L+2 = lane L+1's hole0) ----
        float qx = dpp_down1(hp0x);
        float qy = dpp_down1(hp0y);
        float qz = dpp_down1(hp0z);

        // ---- segment tensions (rsq; eps inside d^2 guards 0-length) ----
        float s0x = hp1x - hp0x, s0y = hp1y - hp0y, s0z = hp1z - hp0z;
        float d2a = fmaf(s0x, s0x, fmaf(s0y, s0y, fmaf(s0z, s0z, 1e-30f)));
        float i0  = STIFF * __builtin_amdgcn_rsqf(d2a);
        float D0x = s0x * i0, D0y = s0y * i0, D0z = s0z * i0;   // segment 2L

        float s1x = qx - hp1x, s1y = qy - hp1y, s1z = qz - hp1z;
        float d2b = fmaf(s1x, s1x, fmaf(s1y, s1y, fmaf(s1z, s1z, 1e-30f)));
        float i1  = STIFF * __builtin_amdgcn_rsqf(d2b);
        float D1x = s1x * i1, D1y = s1y * i1, D1z = s1z * i1;   // segment 2L+1

        // ---- previous-segment tension for hole 2L (lane L-1's D1) ----
        float ex = dpp_up1(D1x);   // lane 0 gets 0 (bound_ctrl)
        float ey = dpp_up1(D1y);
        float ez = dpp_up1(D1z);

        // ---- per-hole forces (DAMP == 1) ----
        float f0x = D0x - ex - u0x;
        float f0y = D0y - ey - u0y;
        float f0z = D0z - ez - u0z;
        float f1x = m1 * D1x - D0x - u1x;
        float f1y = m1 * D1y - D0y - u1y;
        float f1z = m1 * D1z - D0z - u1z;

        // ---- publish f for sparse couplings (rare) ----
        if (anyC) {
            *(float2*)&fH[0][h0] = make_float2(f0x, f1x);
            *(float2*)&fH[1][h0] = make_float2(f0y, f1y);
            *(float2*)&fH[2][h0] = make_float2(f0z, f1z);
        }

        // ---- diag Mf (gravity folded into z) + accumulators (covers fence) --
        float Mf0x = d0 * f0x, Mf0y = d0 * f0y, Mf0z = fmaf(d0, f0z, gz0);
        float Mf1x = d1 * f1x, Mf1y = d1 * f1y, Mf1z = fmaf(d1, f1z, gz1);
        A10x += f0x; A10y += f0y; A10z += f0z;
        A11x += f1x; A11y += f1y; A11z += f1z;
        A20x += A10x; A20y += A10y; A20z += A10z;
        A21x += A11x; A21y += A11y; A21z += A11z;

        // ---- rare off-diagonal couplings ----
        if (anyC) {
            FENCE();
            if (cnt0 > 0) {
                Mf0x += cA0 * fH[0][pA0]; Mf0y += cA0 * fH[1][pA0]; Mf0z += cA0 * fH[2][pA0];
                if (cnt0 > 1) {
                    Mf0x += cA1 * fH[0][pA1]; Mf0y += cA1 * fH[1][pA1]; Mf0z += cA1 * fH[2][pA1];
                    for (int i = 2; i < cnt0; ++i) {
                        int ph = cPart[h0][i]; float cf = cCoef[h0][i];
                        Mf0x += cf * fH[0][ph]; Mf0y += cf * fH[1][ph]; Mf0z += cf * fH[2][ph];
                    }
                }
            }
            if (cnt1 > 0) {
                Mf1x += cB0 * fH[0][pB0]; Mf1y += cB0 * fH[1][pB0]; Mf1z += cB0 * fH[2][pB0];
                if (cnt1 > 1) {
                    Mf1x += cB1 * fH[0][pB1]; Mf1y += cB1 * fH[1][pB1]; Mf1z += cB1 * fH[2][pB1];
                    for (int i = 2; i < cnt1; ++i) {
                        int ph = cPart[h1][i]; float cf = cCoef[h1][i];
                        Mf1x += cf * fH[0][ph]; Mf1y += cf * fH[1][ph]; Mf1z += cf * fH[2][ph];
                    }
                }
            }
        }

        // ---- integrate hole state ----
        u0x += DT * Mf0x; u0y += DT * Mf0y; u0z += DT * Mf0z;
        u1x += DT * Mf1x; u1y += DT * Mf1y; u1z += DT * Mf1z;
        hp0x += DT * u0x; hp0y += DT * u0y; hp0z += DT * u0z;
        hp1x += DT * u1x; hp1y += DT * u1y; hp1z += DT * u1z;
    }

    // ---- publish accumulators, recover node states ----
    *(float4*)&A1H[h0][0] = make_float4(A10x, A10y, A10z, 0.f);
    *(float4*)&A1H[h1][0] = make_float4(A11x, A11y, A11z, 0.f);
    *(float4*)&A2H[h0][0] = make_float4(A20x, A20y, A20z, 0.f);
    *(float4*)&A2H[h1][0] = make_float4(A21x, A21y, A21z, 0.f);
    FENCE();

    const float C1 = (float)NSTEPS * DT;                             // 0.5
    const float C2 = DT * DT * (float)((NSTEPS * (NSTEPS + 1)) / 2); // 0.12525
#pragma unroll
    for (int k = 0; k < 8; ++k) {
        int s = 8 * L + k;
        if (sCanon[s] == s) {
            int id = sId[s];
            float aVx = 0.f, aVy = 0.f, aVz = 0.f, aPx = 0.f, aPy = 0.f, aPz = 0.f;
            int j = s;
            do {
                int hj = j >> 2;
                float w = sW[j];
                aVx += w * A1H[hj][0]; aVy += w * A1H[hj][1]; aVz += w * A1H[hj][2];
                aPx += w * A2H[hj][0]; aPy += w * A2H[hj][1]; aPz += w * A2H[hj][2];
                j = sNext[j];
            } while (j >= 0);
            float im = sIm[s];
            float p0x = node_pos[3 * id + 0], p0y = node_pos[3 * id + 1], p0z = node_pos[3 * id + 2];
            float v0x = node_vel[3 * id + 0], v0y = node_vel[3 * id + 1], v0z = node_vel[3 * id + 2];
            out[3 * id + 0] = p0x + C1 * v0x + (DT * DT) * im * aPx;
            out[3 * id + 1] = p0y + C1 * v0y + (DT * DT) * im * aPy;
            out[3 * id + 2] = p0z + C1 * v0z + C2 * GZ + (DT * DT) * im * aPz;
            out[ncomp + 3 * id + 0] = v0x + DT * im * aVx;
            out[ncomp + 3 * id + 1] = v0y + DT * im * aVy;
            out[ncomp + 3 * id + 2] = v0z + C1 * GZ + DT * im * aVz;
        }
    }
}

extern "C" void kernel_launch(void* const* d_in, const int* in_sizes, int n_in,
                              void* d_out, int out_size, void* d_ws, size_t ws_size,
                              hipStream_t stream) {
    const float* node_pos = (const float*)d_in[0];
    const float* node_vel = (const float*)d_in[1];
    const int*   hole_idx = (const int*)d_in[2];
    const float* hole_w   = (const float*)d_in[3];
    const float* inv_mass = (const float*)d_in[4];
    float* out = (float*)d_out;

    const int ncomp = in_sizes[0];   // 60000 (= N_NODES*3)

    const int BT = 256;
    bulk_integrate<<<(ncomp + BT - 1) / BT, BT, 0, stream>>>(node_pos, node_vel,
                                                             out, ncomp);
    cable_sim<<<1, 256, 0, stream>>>(node_pos, node_vel, hole_idx, hole_w,
                                     inv_mass, out, ncomp);
}

// Round 5
// 179.951 us; speedup vs baseline: 5.2931x; 1.3301x over previous
//
#include <hip/hip_runtime.h>

#define NSTEPS 500
#define DT 1e-3f
#define STIFF 100.0f
#define GZ -9.81f
#define H 128          // holes
#define S 512          // H*4 slots
#define MAXC 12        // max tracked couplings per hole (slow path)

// ---------------------------------------------------------------------------
// Bulk closed-form integration for nodes with zero cable force.
// ---------------------------------------------------------------------------
__global__ void bulk_integrate(const float* __restrict__ pos,
                               const float* __restrict__ vel,
                               float* __restrict__ out, int ncomp) {
    int i = blockIdx.x * blockDim.x + threadIdx.x;
    if (i >= ncomp) return;
    int d = i - (i / 3) * 3;
    float g  = (d == 2) ? GZ : 0.0f;
    float p0 = pos[i];
    float v0 = vel[i];
    const float C1 = (float)NSTEPS * DT;                             // 0.5
    const float C2 = DT * DT * (float)((NSTEPS * (NSTEPS + 1)) / 2); // 0.12525
    out[i]         = p0 + C1 * v0 + C2 * g;
    out[ncomp + i] = v0 + C1 * g;
}

// ---------------------------------------------------------------------------
// Hole-space dynamics, ONE wave. +-1 lane exchange via DPP; sparse coupling
// exchange via ds_bpermute (register crossbar, no LDS write/fence/branch).
// ---------------------------------------------------------------------------
__device__ __forceinline__ float dpp_up1(float x) {   // lane i <- lane i-1
    return __int_as_float(__builtin_amdgcn_update_dpp(
        0, __float_as_int(x), 0x138, 0xF, 0xF, true));
}
__device__ __forceinline__ float dpp_down1(float x) { // lane i <- lane i+1
    return __int_as_float(__builtin_amdgcn_update_dpp(
        0, __float_as_int(x), 0x130, 0xF, 0xF, true));
}

#define FENCE() asm volatile("s_waitcnt lgkmcnt(0)" ::: "memory")

__global__ __launch_bounds__(256) void cable_sim(
    const float* __restrict__ node_pos,
    const float* __restrict__ node_vel,
    const int*   __restrict__ hole_idx,
    const float* __restrict__ hole_w,
    const float* __restrict__ inv_mass,
    float* __restrict__ out, int ncomp) {

    __shared__ int   sId[S];
    __shared__ float sW[S];
    __shared__ float sIm[S];
    __shared__ int   sCanon[S];
    __shared__ int   sNext[S];
    __shared__ float hpH[H][4], hvH[H][4];
    __shared__ float dDiag[H];
    __shared__ float swH[H];
    __shared__ int   cCnt[H];
    __shared__ int   cPart[H][MAXC];
    __shared__ float cCoef[H][MAXC];
    __shared__ float fH[3][H];       // slow path only
    __shared__ float A1H[H][4], A2H[H][4];

    const int tid = threadIdx.x;

    for (int s = tid; s < S; s += 256) {
        int id = hole_idx[s];
        sId[s] = id;
        sW[s]  = hole_w[s];
        sIm[s] = inv_mass[id];
    }
    __syncthreads();

    // ---- per-slot canonical/next chains (final writeback) ----
    {
        int s0 = 2 * tid, s1 = s0 + 1;
        int id0 = sId[s0], id1 = sId[s1];
        int c0 = S, c1 = S, n0 = S, n1 = S;
        for (int j = 0; j < S; ++j) {
            int idj = sId[j];
            if (idj == id0) { if (j < c0) c0 = j; if (j > s0 && j < n0) n0 = j; }
            if (idj == id1) { if (j < c1) c1 = j; if (j > s1 && j < n1) n1 = j; }
        }
        sCanon[s0] = c0;             sCanon[s1] = c1;
        sNext[s0] = (n0 == S) ? -1 : n0;
        sNext[s1] = (n1 == S) ? -1 : n1;
    }

    // ---- per-hole precompute: diag(M), couplings, sum(w), hp0, hv0 ----
    if (tid < H) {
        const int h = tid;
        int myId[4]; float myW[4];
#pragma unroll
        for (int k = 0; k < 4; ++k) { myId[k] = sId[4 * h + k]; myW[k] = sW[4 * h + k]; }
        float dg = 0.f, sw = 0.f;
#pragma unroll
        for (int k = 0; k < 4; ++k) {
            sw += myW[k];
            float imk = sIm[4 * h + k];
#pragma unroll
            for (int l = 0; l < 4; ++l)
                if (myId[k] == myId[l]) dg += myW[k] * myW[l] * imk;
        }
        dDiag[h] = dg;
        swH[h]   = sw;

        int cnt = 0;
        for (int j = 0; j < S; ++j) {
            int hj = j >> 2;
            if (hj == h) continue;
            int idj = sId[j];
            float c = 0.f;
#pragma unroll
            for (int k = 0; k < 4; ++k)
                if (myId[k] == idj) c += myW[k];
            if (c != 0.f) {
                c *= sW[j] * sIm[j];
                int found = -1;
                for (int i = 0; i < cnt; ++i)
                    if (cPart[h][i] == hj) { found = i; break; }
                if (found >= 0) cCoef[h][found] += c;
                else if (cnt < MAXC) { cPart[h][cnt] = hj; cCoef[h][cnt] = c; ++cnt; }
            }
        }
        cCnt[h] = cnt;

        float hx = 0, hy = 0, hz = 0, ux = 0, uy = 0, uz = 0;
#pragma unroll
        for (int k = 0; k < 4; ++k) {
            int id = myId[k]; float w = myW[k];
            hx += w * node_pos[3 * id + 0]; hy += w * node_pos[3 * id + 1]; hz += w * node_pos[3 * id + 2];
            ux += w * node_vel[3 * id + 0]; uy += w * node_vel[3 * id + 1]; uz += w * node_vel[3 * id + 2];
        }
        hpH[h][0] = hx; hpH[h][1] = hy; hpH[h][2] = hz;
        hvH[h][0] = ux; hvH[h][1] = uy; hvH[h][2] = uz;
    }
    __syncthreads();

    if (tid >= 64) return;           // single wave from here
    const int L  = tid;
    const int h0 = 2 * L, h1 = 2 * L + 1;

    float hp0x = hpH[h0][0], hp0y = hpH[h0][1], hp0z = hpH[h0][2];
    float hp1x = hpH[h1][0], hp1y = hpH[h1][1], hp1z = hpH[h1][2];
    float u0x  = hvH[h0][0], u0y  = hvH[h0][1], u0z  = hvH[h0][2];
    float u1x  = hvH[h1][0], u1y  = hvH[h1][1], u1z  = hvH[h1][2];
    const float d0  = dDiag[h0], d1 = dDiag[h1];
    const float gz0 = swH[h0] * GZ, gz1 = swH[h1] * GZ;
    const float m1  = (L == 63) ? 0.f : 1.f;

    const int cnt0 = cCnt[h0], cnt1 = cCnt[h1];
    const int total = cnt0 + cnt1;
    const bool fastOK = __all(total <= 2);

    float A10x = 0.f, A10y = 0.f, A10z = 0.f, A11x = 0.f, A11y = 0.f, A11z = 0.f;
    float A20x = 0.f, A20y = 0.f, A20z = 0.f, A21x = 0.f, A21y = 0.f, A21z = 0.f;

    if (fastOK) {
        // ---- build up to 2 per-lane coupling slots (branchless hot loop) ----
        int ph[2] = {0, 0};  float pc[2] = {0.f, 0.f};  int tg[2] = {0, 0};
        int ns = 0;
        for (int i = 0; i < cnt0 && ns < 2; ++i) { ph[ns] = cPart[h0][i]; pc[ns] = cCoef[h0][i]; tg[ns] = 0; ++ns; }
        for (int i = 0; i < cnt1 && ns < 2; ++i) { ph[ns] = cPart[h1][i]; pc[ns] = cCoef[h1][i]; tg[ns] = 1; ++ns; }
        const int   a0   = ph[0] >> 1,       a1   = ph[1] >> 1;
        const bool  sel0 = (ph[0] & 1) != 0, sel1 = (ph[1] & 1) != 0;
        const float c00  = (tg[0] == 0) ? pc[0] : 0.f;   // slot0 -> Mf0
        const float c01  = (tg[0] == 1) ? pc[0] : 0.f;   // slot0 -> Mf1
        const float c10  = (tg[1] == 0) ? pc[1] : 0.f;
        const float c11  = (tg[1] == 1) ? pc[1] : 0.f;

#pragma unroll 2
        for (int step = 0; step < NSTEPS; ++step) {
            float qx = dpp_down1(hp0x);
            float qy = dpp_down1(hp0y);
            float qz = dpp_down1(hp0z);

            float s0x = hp1x - hp0x, s0y = hp1y - hp0y, s0z = hp1z - hp0z;
            float d2a = fmaf(s0x, s0x, fmaf(s0y, s0y, fmaf(s0z, s0z, 1e-30f)));
            float i0  = STIFF * __builtin_amdgcn_rsqf(d2a);
            float D0x = s0x * i0, D0y = s0y * i0, D0z = s0z * i0;

            float s1x = qx - hp1x, s1y = qy - hp1y, s1z = qz - hp1z;
            float d2b = fmaf(s1x, s1x, fmaf(s1y, s1y, fmaf(s1z, s1z, 1e-30f)));
            float i1  = STIFF * __builtin_amdgcn_rsqf(d2b);
            float D1x = s1x * i1, D1y = s1y * i1, D1z = s1z * i1;

            float ex = dpp_up1(D1x);
            float ey = dpp_up1(D1y);
            float ez = dpp_up1(D1z);

            float f0x = D0x - ex - u0x;
            float f0y = D0y - ey - u0y;
            float f0z = D0z - ez - u0z;
            float f1x = m1 * D1x - D0x - u1x;
            float f1y = m1 * D1y - D0y - u1y;
            float f1z = m1 * D1z - D0z - u1z;

            // ---- coupling exchange: 12 independent bpermutes, no LDS mem ----
            float gAx0 = __shfl(f0x, a0), gAx1 = __shfl(f1x, a0);
            float gAy0 = __shfl(f0y, a0), gAy1 = __shfl(f1y, a0);
            float gAz0 = __shfl(f0z, a0), gAz1 = __shfl(f1z, a0);
            float gBx0 = __shfl(f0x, a1), gBx1 = __shfl(f1x, a1);
            float gBy0 = __shfl(f0y, a1), gBy1 = __shfl(f1y, a1);
            float gBz0 = __shfl(f0z, a1), gBz1 = __shfl(f1z, a1);

            // ---- cover bpermute latency: accumulators + diag Mf ----
            A10x += f0x; A10y += f0y; A10z += f0z;
            A11x += f1x; A11y += f1y; A11z += f1z;
            A20x += A10x; A20y += A10y; A20z += A10z;
            A21x += A11x; A21y += A11y; A21z += A11z;
            float Mf0x = d0 * f0x, Mf0y = d0 * f0y, Mf0z = fmaf(d0, f0z, gz0);
            float Mf1x = d1 * f1x, Mf1y = d1 * f1y, Mf1z = fmaf(d1, f1z, gz1);

            float gAx = sel0 ? gAx1 : gAx0;
            float gAy = sel0 ? gAy1 : gAy0;
            float gAz = sel0 ? gAz1 : gAz0;
            float gBx = sel1 ? gBx1 : gBx0;
            float gBy = sel1 ? gBy1 : gBy0;
            float gBz = sel1 ? gBz1 : gBz0;

            Mf0x = fmaf(c00, gAx, fmaf(c10, gBx, Mf0x));
            Mf0y = fmaf(c00, gAy, fmaf(c10, gBy, Mf0y));
            Mf0z = fmaf(c00, gAz, fmaf(c10, gBz, Mf0z));
            Mf1x = fmaf(c01, gAx, fmaf(c11, gBx, Mf1x));
            Mf1y = fmaf(c01, gAy, fmaf(c11, gBy, Mf1y));
            Mf1z = fmaf(c01, gAz, fmaf(c11, gBz, Mf1z));

            u0x += DT * Mf0x; u0y += DT * Mf0y; u0z += DT * Mf0z;
            u1x += DT * Mf1x; u1y += DT * Mf1y; u1z += DT * Mf1z;
            hp0x += DT * u0x; hp0y += DT * u0y; hp0z += DT * u0z;
            hp1x += DT * u1x; hp1y += DT * u1y; hp1z += DT * u1z;
        }
    } else {
        // ---- slow fallback: LDS publish + fence (general couplings) ----
        int   pA0 = 0, pA1 = 0, pB0 = 0, pB1 = 0;
        float cA0 = 0.f, cA1 = 0.f, cB0 = 0.f, cB1 = 0.f;
        if (cnt0 > 0) { pA0 = cPart[h0][0]; cA0 = cCoef[h0][0]; }
        if (cnt0 > 1) { pA1 = cPart[h0][1]; cA1 = cCoef[h0][1]; }
        if (cnt1 > 0) { pB0 = cPart[h1][0]; cB0 = cCoef[h1][0]; }
        if (cnt1 > 1) { pB1 = cPart[h1][1]; cB1 = cCoef[h1][1]; }

        for (int step = 0; step < NSTEPS; ++step) {
            float qx = dpp_down1(hp0x);
            float qy = dpp_down1(hp0y);
            float qz = dpp_down1(hp0z);

            float s0x = hp1x - hp0x, s0y = hp1y - hp0y, s0z = hp1z - hp0z;
            float d2a = fmaf(s0x, s0x, fmaf(s0y, s0y, fmaf(s0z, s0z, 1e-30f)));
            float i0  = STIFF * __builtin_amdgcn_rsqf(d2a);
            float D0x = s0x * i0, D0y = s0y * i0, D0z = s0z * i0;

            float s1x = qx - hp1x, s1y = qy - hp1y, s1z = qz - hp1z;
            float d2b = fmaf(s1x, s1x, fmaf(s1y, s1y, fmaf(s1z, s1z, 1e-30f)));
            float i1  = STIFF * __builtin_amdgcn_rsqf(d2b);
            float D1x = s1x * i1, D1y = s1y * i1, D1z = s1z * i1;

            float ex = dpp_up1(D1x);
            float ey = dpp_up1(D1y);
            float ez = dpp_up1(D1z);

            float f0x = D0x - ex - u0x;
            float f0y = D0y - ey - u0y;
            float f0z = D0z - ez - u0z;
            float f1x = m1 * D1x - D0x - u1x;
            float f1y = m1 * D1y - D0y - u1y;
            float f1z = m1 * D1z - D0z - u1z;

            *(float2*)&fH[0][h0] = make_float2(f0x, f1x);
            *(float2*)&fH[1][h0] = make_float2(f0y, f1y);
            *(float2*)&fH[2][h0] = make_float2(f0z, f1z);

            float Mf0x = d0 * f0x, Mf0y = d0 * f0y, Mf0z = fmaf(d0, f0z, gz0);
            float Mf1x = d1 * f1x, Mf1y = d1 * f1y, Mf1z = fmaf(d1, f1z, gz1);
            A10x += f0x; A10y += f0y; A10z += f0z;
            A11x += f1x; A11y += f1y; A11z += f1z;
            A20x += A10x; A20y += A10y; A20z += A10z;
            A21x += A11x; A21y += A11y; A21z += A11z;

            FENCE();
            if (cnt0 > 0) {
                Mf0x += cA0 * fH[0][pA0]; Mf0y += cA0 * fH[1][pA0]; Mf0z += cA0 * fH[2][pA0];
                if (cnt0 > 1) {
                    Mf0x += cA1 * fH[0][pA1]; Mf0y += cA1 * fH[1][pA1]; Mf0z += cA1 * fH[2][pA1];
                    for (int i = 2; i < cnt0; ++i) {
                        int p = cPart[h0][i]; float cf = cCoef[h0][i];
                        Mf0x += cf * fH[0][p]; Mf0y += cf * fH[1][p]; Mf0z += cf * fH[2][p];
                    }
                }
            }
            if (cnt1 > 0) {
                Mf1x += cB0 * fH[0][pB0]; Mf1y += cB0 * fH[1][pB0]; Mf1z += cB0 * fH[2][pB0];
                if (cnt1 > 1) {
                    Mf1x += cB1 * fH[0][pB1]; Mf1y += cB1 * fH[1][pB1]; Mf1z += cB1 * fH[2][pB1];
                    for (int i = 2; i < cnt1; ++i) {
                        int p = cPart[h1][i]; float cf = cCoef[h1][i];
                        Mf1x += cf * fH[0][p]; Mf1y += cf * fH[1][p]; Mf1z += cf * fH[2][p];
                    }
                }
            }
            FENCE();

            u0x += DT * Mf0x; u0y += DT * Mf0y; u0z += DT * Mf0z;
            u1x += DT * Mf1x; u1y += DT * Mf1y; u1z += DT * Mf1z;
            hp0x += DT * u0x; hp0y += DT * u0y; hp0z += DT * u0z;
            hp1x += DT * u1x; hp1y += DT * u1y; hp1z += DT * u1z;
        }
    }

    // ---- publish accumulators, recover node states ----
    *(float4*)&A1H[h0][0] = make_float4(A10x, A10y, A10z, 0.f);
    *(float4*)&A1H[h1][0] = make_float4(A11x, A11y, A11z, 0.f);
    *(float4*)&A2H[h0][0] = make_float4(A20x, A20y, A20z, 0.f);
    *(float4*)&A2H[h1][0] = make_float4(A21x, A21y, A21z, 0.f);
    FENCE();

    const float C1 = (float)NSTEPS * DT;                             // 0.5
    const float C2 = DT * DT * (float)((NSTEPS * (NSTEPS + 1)) / 2); // 0.12525
#pragma unroll
    for (int k = 0; k < 8; ++k) {
        int s = 8 * L + k;
        if (sCanon[s] == s) {
            int id = sId[s];
            float aVx = 0.f, aVy = 0.f, aVz = 0.f, aPx = 0.f, aPy = 0.f, aPz = 0.f;
            int j = s;
            do {
                int hj = j >> 2;
                float w = sW[j];
                aVx += w * A1H[hj][0]; aVy += w * A1H[hj][1]; aVz += w * A1H[hj][2];
                aPx += w * A2H[hj][0]; aPy += w * A2H[hj][1]; aPz += w * A2H[hj][2];
                j = sNext[j];
            } while (j >= 0);
            float im = sIm[s];
            float p0x = node_pos[3 * id + 0], p0y = node_pos[3 * id + 1], p0z = node_pos[3 * id + 2];
            float v0x = node_vel[3 * id + 0], v0y = node_vel[3 * id + 1], v0z = node_vel[3 * id + 2];
            out[3 * id + 0] = p0x + C1 * v0x + (DT * DT) * im * aPx;
            out[3 * id + 1] = p0y + C1 * v0y + (DT * DT) * im * aPy;
            out[3 * id + 2] = p0z + C1 * v0z + C2 * GZ + (DT * DT) * im * aPz;
            out[ncomp + 3 * id + 0] = v0x + DT * im * aVx;
            out[ncomp + 3 * id + 1] = v0y + DT * im * aVy;
            out[ncomp + 3 * id + 2] = v0z + C1 * GZ + DT * im * aVz;
        }
    }
}

extern "C" void kernel_launch(void* const* d_in, const int* in_sizes, int n_in,
                              void* d_out, int out_size, void* d_ws, size_t ws_size,
                              hipStream_t stream) {
    const float* node_pos = (const float*)d_in[0];
    const float* node_vel = (const float*)d_in[1];
    const int*   hole_idx = (const int*)d_in[2];
    const float* hole_w   = (const float*)d_in[3];
    const float* inv_mass = (const float*)d_in[4];
    float* out = (float*)d_out;

    const int ncomp = in_sizes[0];   // 60000

    const int BT = 256;
    bulk_integrate<<<(ncomp + BT - 1) / BT, BT, 0, stream>>>(node_pos, node_vel,
                                                             out, ncomp);
    cable_sim<<<1, 256, 0, stream>>>(node_pos, node_vel, hole_idx, hole_w,
                                     inv_mass, out, ncomp);
}

// Round 6
// 170.885 us; speedup vs baseline: 5.5740x; 1.0531x over previous
//
#include <hip/hip_runtime.h>

#define NSTEPS 500
#define DT 1e-3f
#define DTDT 1e-6f
#define STIFF 100.0f
#define GZ -9.81f
#define H 128          // holes
#define S 512          // H*4 slots
#define MAXC 12        // max tracked couplings per hole (slow path)

// ---------------------------------------------------------------------------
// Bulk closed-form integration for nodes with zero cable force.
// ---------------------------------------------------------------------------
__global__ void bulk_integrate(const float* __restrict__ pos,
                               const float* __restrict__ vel,
                               float* __restrict__ out, int ncomp) {
    int i = blockIdx.x * blockDim.x + threadIdx.x;
    if (i >= ncomp) return;
    int d = i - (i / 3) * 3;
    float g  = (d == 2) ? GZ : 0.0f;
    float p0 = pos[i];
    float v0 = vel[i];
    const float C1 = (float)NSTEPS * DT;                             // 0.5
    const float C2 = DT * DT * (float)((NSTEPS * (NSTEPS + 1)) / 2); // 0.12525
    out[i]         = p0 + C1 * v0 + C2 * g;
    out[ncomp + i] = v0 + C1 * g;
}

__device__ __forceinline__ float dpp_up1(float x) {   // lane i <- lane i-1
    return __int_as_float(__builtin_amdgcn_update_dpp(
        0, __float_as_int(x), 0x138, 0xF, 0xF, true));
}
__device__ __forceinline__ float dpp_down1(float x) { // lane i <- lane i+1
    return __int_as_float(__builtin_amdgcn_update_dpp(
        0, __float_as_int(x), 0x130, 0xF, 0xF, true));
}

#define FENCE() asm volatile("s_waitcnt lgkmcnt(0)" ::: "memory")

__global__ __launch_bounds__(256) void cable_sim(
    const float* __restrict__ node_pos,
    const float* __restrict__ node_vel,
    const int*   __restrict__ hole_idx,
    const float* __restrict__ hole_w,
    const float* __restrict__ inv_mass,
    float* __restrict__ out, int ncomp) {

    __shared__ int   sId[S];
    __shared__ float sW[S];
    __shared__ float sIm[S];
    __shared__ int   sCanon[S];
    __shared__ int   sNext[S];
    __shared__ float hpH[H][4], hvH[H][4];
    __shared__ float dDiag[H];
    __shared__ float swH[H];
    __shared__ int   cCnt[H];
    __shared__ int   cPart[H][MAXC];
    __shared__ float cCoef[H][MAXC];
    __shared__ float fH[3][H];       // slow path only
    __shared__ float A1H[H][4], A2H[H][4];
    __shared__ int   pubSel[64];     // which f (0/1) each source lane publishes
    __shared__ int   pubConflict;

    const int tid = threadIdx.x;

    for (int s = tid; s < S; s += 256) {
        int id = hole_idx[s];
        sId[s] = id;
        sW[s]  = hole_w[s];
        sIm[s] = inv_mass[id];
    }
    __syncthreads();

    // ---- per-slot canonical/next chains (final writeback) ----
    {
        int s0 = 2 * tid, s1 = s0 + 1;
        int id0 = sId[s0], id1 = sId[s1];
        int c0 = S, c1 = S, n0 = S, n1 = S;
        for (int j = 0; j < S; ++j) {
            int idj = sId[j];
            if (idj == id0) { if (j < c0) c0 = j; if (j > s0 && j < n0) n0 = j; }
            if (idj == id1) { if (j < c1) c1 = j; if (j > s1 && j < n1) n1 = j; }
        }
        sCanon[s0] = c0;             sCanon[s1] = c1;
        sNext[s0] = (n0 == S) ? -1 : n0;
        sNext[s1] = (n1 == S) ? -1 : n1;
    }

    // ---- per-hole precompute: diag(M), couplings, sum(w), hp0, hv0 ----
    if (tid < H) {
        const int h = tid;
        int myId[4]; float myW[4];
#pragma unroll
        for (int k = 0; k < 4; ++k) { myId[k] = sId[4 * h + k]; myW[k] = sW[4 * h + k]; }
        float dg = 0.f, sw = 0.f;
#pragma unroll
        for (int k = 0; k < 4; ++k) {
            sw += myW[k];
            float imk = sIm[4 * h + k];
#pragma unroll
            for (int l = 0; l < 4; ++l)
                if (myId[k] == myId[l]) dg += myW[k] * myW[l] * imk;
        }
        dDiag[h] = dg;
        swH[h]   = sw;

        int cnt = 0;
        for (int j = 0; j < S; ++j) {
            int hj = j >> 2;
            if (hj == h) continue;
            int idj = sId[j];
            float c = 0.f;
#pragma unroll
            for (int k = 0; k < 4; ++k)
                if (myId[k] == idj) c += myW[k];
            if (c != 0.f) {
                c *= sW[j] * sIm[j];
                int found = -1;
                for (int i = 0; i < cnt; ++i)
                    if (cPart[h][i] == hj) { found = i; break; }
                if (found >= 0) cCoef[h][found] += c;
                else if (cnt < MAXC) { cPart[h][cnt] = hj; cCoef[h][cnt] = c; ++cnt; }
            }
        }
        cCnt[h] = cnt;

        float hx = 0, hy = 0, hz = 0, ux = 0, uy = 0, uz = 0;
#pragma unroll
        for (int k = 0; k < 4; ++k) {
            int id = myId[k]; float w = myW[k];
            hx += w * node_pos[3 * id + 0]; hy += w * node_pos[3 * id + 1]; hz += w * node_pos[3 * id + 2];
            ux += w * node_vel[3 * id + 0]; uy += w * node_vel[3 * id + 1]; uz += w * node_vel[3 * id + 2];
        }
        hpH[h][0] = hx; hpH[h][1] = hy; hpH[h][2] = hz;
        hvH[h][0] = ux; hvH[h][1] = uy; hvH[h][2] = uz;
    }
    __syncthreads();

    // ---- publish-selection: each source lane must serve ONE element ----
    if (tid == 0) {
        pubConflict = 0;
        for (int l = 0; l < 64; ++l) pubSel[l] = -1;
        for (int h = 0; h < H; ++h) {
            int cnt = cCnt[h];
            for (int i = 0; i < cnt; ++i) {
                int p  = cPart[h][i];
                int sl = p >> 1, e = p & 1;
                if (pubSel[sl] == -1) pubSel[sl] = e;
                else if (pubSel[sl] != e) pubConflict = 1;
            }
        }
    }
    __syncthreads();

    if (tid >= 64) return;           // single wave from here
    const int L  = tid;
    const int h0 = 2 * L, h1 = 2 * L + 1;

    float hp0x = hpH[h0][0], hp0y = hpH[h0][1], hp0z = hpH[h0][2];
    float hp1x = hpH[h1][0], hp1y = hpH[h1][1], hp1z = hpH[h1][2];
    float u0x  = hvH[h0][0], u0y  = hvH[h0][1], u0z  = hvH[h0][2];
    float u1x  = hvH[h1][0], u1y  = hvH[h1][1], u1z  = hvH[h1][2];
    const float d0  = dDiag[h0], d1 = dDiag[h1];
    const float gz0 = swH[h0] * GZ, gz1 = swH[h1] * GZ;
    const float m1  = (L == 63) ? 0.f : 1.f;

    const int cnt0 = cCnt[h0], cnt1 = cCnt[h1];
    const int total = cnt0 + cnt1;
    const bool fastOK = __all(total <= 2) && (pubConflict == 0);

    float A10x = 0.f, A10y = 0.f, A10z = 0.f, A11x = 0.f, A11y = 0.f, A11z = 0.f;
    float A20x = 0.f, A20y = 0.f, A20z = 0.f, A21x = 0.f, A21y = 0.f, A21z = 0.f;

    if (fastOK) {
        // ---- per-lane coupling slots; partner publishes the right element ----
        int ph[2] = {0, 0};  float pc[2] = {0.f, 0.f};  int tg[2] = {0, 0};
        int ns = 0;
        for (int i = 0; i < cnt0 && ns < 2; ++i) { ph[ns] = cPart[h0][i]; pc[ns] = cCoef[h0][i]; tg[ns] = 0; ++ns; }
        for (int i = 0; i < cnt1 && ns < 2; ++i) { ph[ns] = cPart[h1][i]; pc[ns] = cCoef[h1][i]; tg[ns] = 1; ++ns; }
        const int   a0 = ph[0] >> 1, a1 = ph[1] >> 1;
        // routing coeffs pre-scaled by dt (u-fold) and dt^2 (hp-fold)
        const float dcA0  = (tg[0] == 0) ? DT   * pc[0] : 0.f;
        const float dcA1  = (tg[0] == 1) ? DT   * pc[0] : 0.f;
        const float dcB0  = (tg[1] == 0) ? DT   * pc[1] : 0.f;
        const float dcB1  = (tg[1] == 1) ? DT   * pc[1] : 0.f;
        const float d2cA0 = (tg[0] == 0) ? DTDT * pc[0] : 0.f;
        const float d2cA1 = (tg[0] == 1) ? DTDT * pc[0] : 0.f;
        const float d2cB0 = (tg[1] == 0) ? DTDT * pc[1] : 0.f;
        const float d2cB1 = (tg[1] == 1) ? DTDT * pc[1] : 0.f;
        const int   pe = (pubSel[L] == 1) ? 1 : 0;

        // pipelined coupling registers: bpermute results of f_{t-1}
        float ngAx = 0.f, ngAy = 0.f, ngAz = 0.f;
        float ngBx = 0.f, ngBy = 0.f, ngBz = 0.f;

#pragma unroll 2
        for (int step = 0; step < NSTEPS; ++step) {
            // ---- segment chain on hp (hp misses dt^2*C_{t-1}: ~1e-4, D-only) ----
            float qx = dpp_down1(hp0x);
            float qy = dpp_down1(hp0y);
            float qz = dpp_down1(hp0z);

            float s0x = hp1x - hp0x, s0y = hp1y - hp0y, s0z = hp1z - hp0z;
            float d2a = fmaf(s0x, s0x, fmaf(s0y, s0y, fmaf(s0z, s0z, 1e-30f)));
            float i0  = STIFF * __builtin_amdgcn_rsqf(d2a);
            float D0x = s0x * i0, D0y = s0y * i0, D0z = s0z * i0;

            float s1x = qx - hp1x, s1y = qy - hp1y, s1z = qz - hp1z;
            float d2b = fmaf(s1x, s1x, fmaf(s1y, s1y, fmaf(s1z, s1z, 1e-30f)));
            float i1  = STIFF * __builtin_amdgcn_rsqf(d2b);
            float D1x = s1x * i1, D1y = s1y * i1, D1z = s1z * i1;

            float ex = dpp_up1(D1x);
            float ey = dpp_up1(D1y);
            float ez = dpp_up1(D1z);

            // ---- exact u_t: fold dt*C_{t-1} (bpermutes issued last iter) ----
            u0x = fmaf(dcA0, ngAx, fmaf(dcB0, ngBx, u0x));
            u0y = fmaf(dcA0, ngAy, fmaf(dcB0, ngBy, u0y));
            u0z = fmaf(dcA0, ngAz, fmaf(dcB0, ngBz, u0z));
            u1x = fmaf(dcA1, ngAx, fmaf(dcB1, ngBx, u1x));
            u1y = fmaf(dcA1, ngAy, fmaf(dcB1, ngBy, u1y));
            u1z = fmaf(dcA1, ngAz, fmaf(dcB1, ngBz, u1z));

            // ---- forces ----
            float f0x = D0x - ex - u0x;
            float f0y = D0y - ey - u0y;
            float f0z = D0z - ez - u0z;
            float f1x = fmaf(m1, D1x, -D0x) - u1x;
            float f1y = fmaf(m1, D1y, -D0y) - u1y;
            float f1z = fmaf(m1, D1z, -D0z) - u1z;

            // ---- hp fold of dt^2*C_{t-1} (late; latency long gone) ----
            float hq0x = fmaf(d2cA0, ngAx, fmaf(d2cB0, ngBx, hp0x));
            float hq0y = fmaf(d2cA0, ngAy, fmaf(d2cB0, ngBy, hp0y));
            float hq0z = fmaf(d2cA0, ngAz, fmaf(d2cB0, ngBz, hp0z));
            float hq1x = fmaf(d2cA1, ngAx, fmaf(d2cB1, ngBx, hp1x));
            float hq1y = fmaf(d2cA1, ngAy, fmaf(d2cB1, ngBy, hp1y));
            float hq1z = fmaf(d2cA1, ngAz, fmaf(d2cB1, ngBz, hp1z));

            // ---- publish-select + issue bpermutes for NEXT iteration ----
            float fpx = pe ? f1x : f0x;
            float fpy = pe ? f1y : f0y;
            float fpz = pe ? f1z : f0z;
            ngAx = __shfl(fpx, a0); ngAy = __shfl(fpy, a0); ngAz = __shfl(fpz, a0);
            ngBx = __shfl(fpx, a1); ngBy = __shfl(fpy, a1); ngBz = __shfl(fpz, a1);

            // ---- diag Mf + accumulators ----
            float Mf0x = d0 * f0x, Mf0y = d0 * f0y, Mf0z = fmaf(d0, f0z, gz0);
            float Mf1x = d1 * f1x, Mf1y = d1 * f1y, Mf1z = fmaf(d1, f1z, gz1);
            A10x += f0x; A10y += f0y; A10z += f0z;
            A11x += f1x; A11y += f1y; A11z += f1z;
            A20x += A10x; A20y += A10y; A20z += A10z;
            A21x += A11x; A21y += A11y; A21z += A11z;

            // ---- integrate (u missing dt*C_t, hp missing dt^2*C_t) ----
            u0x = fmaf(DT, Mf0x, u0x); u0y = fmaf(DT, Mf0y, u0y); u0z = fmaf(DT, Mf0z, u0z);
            u1x = fmaf(DT, Mf1x, u1x); u1y = fmaf(DT, Mf1y, u1y); u1z = fmaf(DT, Mf1z, u1z);
            hp0x = fmaf(DT, u0x, hq0x); hp0y = fmaf(DT, u0y, hq0y); hp0z = fmaf(DT, u0z, hq0z);
            hp1x = fmaf(DT, u1x, hq1x); hp1y = fmaf(DT, u1y, hq1y); hp1z = fmaf(DT, u1z, hq1z);
        }
    } else {
        // ---- slow fallback: LDS publish + fence (general couplings) ----
        int   pA0 = 0, pA1 = 0, pB0 = 0, pB1 = 0;
        float cA0 = 0.f, cA1 = 0.f, cB0 = 0.f, cB1 = 0.f;
        if (cnt0 > 0) { pA0 = cPart[h0][0]; cA0 = cCoef[h0][0]; }
        if (cnt0 > 1) { pA1 = cPart[h0][1]; cA1 = cCoef[h0][1]; }
        if (cnt1 > 0) { pB0 = cPart[h1][0]; cB0 = cCoef[h1][0]; }
        if (cnt1 > 1) { pB1 = cPart[h1][1]; cB1 = cCoef[h1][1]; }

        for (int step = 0; step < NSTEPS; ++step) {
            float qx = dpp_down1(hp0x);
            float qy = dpp_down1(hp0y);
            float qz = dpp_down1(hp0z);

            float s0x = hp1x - hp0x, s0y = hp1y - hp0y, s0z = hp1z - hp0z;
            float d2a = fmaf(s0x, s0x, fmaf(s0y, s0y, fmaf(s0z, s0z, 1e-30f)));
            float i0  = STIFF * __builtin_amdgcn_rsqf(d2a);
            float D0x = s0x * i0, D0y = s0y * i0, D0z = s0z * i0;

            float s1x = qx - hp1x, s1y = qy - hp1y, s1z = qz - hp1z;
            float d2b = fmaf(s1x, s1x, fmaf(s1y, s1y, fmaf(s1z, s1z, 1e-30f)));
            float i1  = STIFF * __builtin_amdgcn_rsqf(d2b);
            float D1x = s1x * i1, D1y = s1y * i1, D1z = s1z * i1;

            float ex = dpp_up1(D1x);
            float ey = dpp_up1(D1y);
            float ez = dpp_up1(D1z);

            float f0x = D0x - ex - u0x;
            float f0y = D0y - ey - u0y;
            float f0z = D0z - ez - u0z;
            float f1x = fmaf(m1, D1x, -D0x) - u1x;
            float f1y = fmaf(m1, D1y, -D0y) - u1y;
            float f1z = fmaf(m1, D1z, -D0z) - u1z;

            *(float2*)&fH[0][h0] = make_float2(f0x, f1x);
            *(float2*)&fH[1][h0] = make_float2(f0y, f1y);
            *(float2*)&fH[2][h0] = make_float2(f0z, f1z);

            float Mf0x = d0 * f0x, Mf0y = d0 * f0y, Mf0z = fmaf(d0, f0z, gz0);
            float Mf1x = d1 * f1x, Mf1y = d1 * f1y, Mf1z = fmaf(d1, f1z, gz1);
            A10x += f0x; A10y += f0y; A10z += f0z;
            A11x += f1x; A11y += f1y; A11z += f1z;
            A20x += A10x; A20y += A10y; A20z += A10z;
            A21x += A11x; A21y += A11y; A21z += A11z;

            FENCE();
            if (cnt0 > 0) {
                Mf0x += cA0 * fH[0][pA0]; Mf0y += cA0 * fH[1][pA0]; Mf0z += cA0 * fH[2][pA0];
                if (cnt0 > 1) {
                    Mf0x += cA1 * fH[0][pA1]; Mf0y += cA1 * fH[1][pA1]; Mf0z += cA1 * fH[2][pA1];
                    for (int i = 2; i < cnt0; ++i) {
                        int p = cPart[h0][i]; float cf = cCoef[h0][i];
                        Mf0x += cf * fH[0][p]; Mf0y += cf * fH[1][p]; Mf0z += cf * fH[2][p];
                    }
                }
            }
            if (cnt1 > 0) {
                Mf1x += cB0 * fH[0][pB0]; Mf1y += cB0 * fH[1][pB0]; Mf1z += cB0 * fH[2][pB0];
                if (cnt1 > 1) {
                    Mf1x += cB1 * fH[0][pB1]; Mf1y += cB1 * fH[1][pB1]; Mf1z += cB1 * fH[2][pB1];
                    for (int i = 2; i < cnt1; ++i) {
                        int p = cPart[h1][i]; float cf = cCoef[h1][i];
                        Mf1x += cf * fH[0][p]; Mf1y += cf * fH[1][p]; Mf1z += cf * fH[2][p];
                    }
                }
            }
            FENCE();

            u0x += DT * Mf0x; u0y += DT * Mf0y; u0z += DT * Mf0z;
            u1x += DT * Mf1x; u1y += DT * Mf1y; u1z += DT * Mf1z;
            hp0x += DT * u0x; hp0y += DT * u0y; hp0z += DT * u0z;
            hp1x += DT * u1x; hp1y += DT * u1y; hp1z += DT * u1z;
        }
    }

    // ---- publish accumulators, recover node states ----
    *(float4*)&A1H[h0][0] = make_float4(A10x, A10y, A10z, 0.f);
    *(float4*)&A1H[h1][0] = make_float4(A11x, A11y, A11z, 0.f);
    *(float4*)&A2H[h0][0] = make_float4(A20x, A20y, A20z, 0.f);
    *(float4*)&A2H[h1][0] = make_float4(A21x, A21y, A21z, 0.f);
    FENCE();

    const float C1 = (float)NSTEPS * DT;                             // 0.5
    const float C2 = DT * DT * (float)((NSTEPS * (NSTEPS + 1)) / 2); // 0.12525
#pragma unroll
    for (int k = 0; k < 8; ++k) {
        int s = 8 * L + k;
        if (sCanon[s] == s) {
            int id = sId[s];
            float aVx = 0.f, aVy = 0.f, aVz = 0.f, aPx = 0.f, aPy = 0.f, aPz = 0.f;
            int j = s;
            do {
                int hj = j >> 2;
                float w = sW[j];
                aVx += w * A1H[hj][0]; aVy += w * A1H[hj][1]; aVz += w * A1H[hj][2];
                aPx += w * A2H[hj][0]; aPy += w * A2H[hj][1]; aPz += w * A2H[hj][2];
                j = sNext[j];
            } while (j >= 0);
            float im = sIm[s];
            float p0x = node_pos[3 * id + 0], p0y = node_pos[3 * id + 1], p0z = node_pos[3 * id + 2];
            float v0x = node_vel[3 * id + 0], v0y = node_vel[3 * id + 1], v0z = node_vel[3 * id + 2];
            out[3 * id + 0] = p0x + C1 * v0x + (DT * DT) * im * aPx;
            out[3 * id + 1] = p0y + C1 * v0y + (DT * DT) * im * aPy;
            out[3 * id + 2] = p0z + C1 * v0z + C2 * GZ + (DT * DT) * im * aPz;
            out[ncomp + 3 * id + 0] = v0x + DT * im * aVx;
            out[ncomp + 3 * id + 1] = v0y + DT * im * aVy;
            out[ncomp + 3 * id + 2] = v0z + C1 * GZ + DT * im * aVz;
        }
    }
}

extern "C" void kernel_launch(void* const* d_in, const int* in_sizes, int n_in,
                              void* d_out, int out_size, void* d_ws, size_t ws_size,
                              hipStream_t stream) {
    const float* node_pos = (const float*)d_in[0];
    const float* node_vel = (const float*)d_in[1];
    const int*   hole_idx = (const int*)d_in[2];
    const float* hole_w   = (const float*)d_in[3];
    const float* inv_mass = (const float*)d_in[4];
    float* out = (float*)d_out;

    const int ncomp = in_sizes[0];   // 60000

    const int BT = 256;
    bulk_integrate<<<(ncomp + BT - 1) / BT, BT, 0, stream>>>(node_pos, node_vel,
                                                             out, ncomp);
    cable_sim<<<1, 256, 0, stream>>>(node_pos, node_vel, hole_idx, hole_w,
                                     inv_mass, out, ncomp);
}